// Round 15
// baseline (546.269 us; speedup 1.0000x reference)
//
#include <hip/hip_runtime.h>
#include <math.h>

// Problem geometry (fixed by reference): T=4, B=32, N=1024, C=256
#define MROWS   131072      // T*B*N rows, C contiguous
#define CCH     256
#define TSTEPS  4
#define SSLICE  8388608     // B*N*C (one timestep slice)
#define BM      64
#define BN      64
#define BK      16
#define LDP     68
#define MTILES  2048        // MROWS/BM (for k2 partials)

typedef float  f32x4  __attribute__((ext_vector_type(4)));
typedef short  bf16x8 __attribute__((ext_vector_type(8)));

__device__ __forceinline__ float sigmoidf_(float x) {
    return 1.0f / (1.0f + __expf(-x));
}

// Exact 3-way bf16 split of a pair of fp32 values, packed k-pairwise into dwords.
// d0 = (bf16hi(y0)<<16)|bf16hi(x0) etc. Pack order identical for A and B paths,
// so any pack-order convention cancels inside MFMA.
__device__ __forceinline__ void split_pair(float x, float y, unsigned& d0, unsigned& d1, unsigned& d2) {
    unsigned ux = __float_as_uint(x), uy = __float_as_uint(y);
    unsigned ux0 = ux & 0xffff0000u, uy0 = uy & 0xffff0000u;
    float rx = x - __uint_as_float(ux0), ry = y - __uint_as_float(uy0);
    unsigned ux1 = __float_as_uint(rx) & 0xffff0000u, uy1 = __float_as_uint(ry) & 0xffff0000u;
    float r2x = rx - __uint_as_float(ux1), r2y = ry - __uint_as_float(uy1);
    d0 = __builtin_amdgcn_perm(uy0, ux0, 0x07060302u);
    d1 = __builtin_amdgcn_perm(uy1, ux1, 0x07060302u);
    unsigned pk;
    asm("v_cvt_pk_bf16_f32 %0, %1, %2" : "=v"(pk) : "v"(r2x), "v"(r2y));
    d2 = pk;
}

// ---------------------------------------------------------------------------
// K0: pre-split W_att, W_lsm into bf16x3 planes, frag-ordered:
// wsplit[(((t*3+p)*16 + ncf)*8 + kc)*64 + l] = 16B chunk for lane l:
//   n = ncf*16 + (l&15), k = kc*32 + (l>>4)*8 + e
// ---------------------------------------------------------------------------
__global__ __launch_bounds__(256) void k0_splitw(
    const float* __restrict__ Wa, const float* __restrict__ Wl,
    int4* __restrict__ wsplit)
{
    const int gid = blockIdx.x * 256 + threadIdx.x;  // 0..16383
    const int t   = gid >> 13;
    const int rem = gid & 8191;
    const int ncf = rem >> 9;         // 0..15
    const int kc  = (rem >> 6) & 7;   // 0..7
    const int l   = rem & 63;
    const int n   = ncf * 16 + (l & 15);
    const int k0  = kc * 32 + (l >> 4) * 8;
    const float* W = t ? Wl : Wa;

    float v[8];
    *(float4*)&v[0] = *(const float4*)(W + n * 256 + k0);
    *(float4*)&v[4] = *(const float4*)(W + n * 256 + k0 + 4);

    unsigned d0[4], d1[4], d2[4];
    #pragma unroll
    for (int j = 0; j < 4; ++j)
        split_pair(v[2*j], v[2*j+1], d0[j], d1[j], d2[j]);

    wsplit[(((t*3+0)*16 + ncf)*8 + kc)*64 + l] = make_int4(d0[0], d0[1], d0[2], d0[3]);
    wsplit[(((t*3+1)*16 + ncf)*8 + kc)*64 + l] = make_int4(d1[0], d1[1], d1[2], d1[3]);
    wsplit[(((t*3+2)*16 + ncf)*8 + kc)*64 + l] = make_int4(d2[0], d2[1], d2[2], d2[3]);
}

// ---------------------------------------------------------------------------
// K1: dual GEMM via bf16x3-split MFMA emulation + sigmoid gates + cross fuse.
// BM=128, BN=256 (full N), 512 threads = 8 waves (2M x 4N), wave tile 64x64.
// A (x_attn, x_lsm) split in-kernel into LDS; B from pre-split planes (L2-hot).
// EXACT R2/R13 champion: single-buffered LDS, 2 barriers/kc, NO setprio.
// ---------------------------------------------------------------------------
__global__ __launch_bounds__(512, 2) void k1_mfma(
    const float* __restrict__ A1, const float* __restrict__ A2,
    const int4* __restrict__ wsplit,
    const float* __restrict__ ba, const float* __restrict__ bl,
    float* __restrict__ fused)
{
    __shared__ int4 AsV[2*3*4*128];   // [t][p][k8][row] 16B chunks = 48 KB

    const int tid = threadIdx.x;
    const int l   = tid & 63;
    const int w   = tid >> 6;
    const int rw  = (w >> 2) * 64;    // wave M offset
    const int nw  = (w & 3) * 64;     // wave N offset
    const int m0  = blockIdx.x * 128;

    // staging assignment: 512 threads cover 2 tensors x 128 rows x 2 k-halves
    const int st_t   = tid >> 8;
    const int st_row = (tid & 255) >> 1;
    const int st_kh  = tid & 1;
    const float* Ag  = (st_t ? A2 : A1) + (size_t)(m0 + st_row) * 256 + st_kh * 16;

    f32x4 acc[2][4][4] = {};

    float va[16];
    #pragma unroll
    for (int q = 0; q < 4; ++q)
        *(float4*)&va[q*4] = *(const float4*)(Ag + q*4);

    for (int kc = 0; kc < 8; ++kc) {
        __syncthreads();   // previous compute done reading LDS
        #pragma unroll
        for (int g = 0; g < 2; ++g) {
            unsigned d0[4], d1[4], d2[4];
            #pragma unroll
            for (int j = 0; j < 4; ++j)
                split_pair(va[g*8 + 2*j], va[g*8 + 2*j + 1], d0[j], d1[j], d2[j]);
            const int k8 = st_kh * 2 + g;
            AsV[((st_t*3+0)*4 + k8)*128 + st_row] = make_int4(d0[0], d0[1], d0[2], d0[3]);
            AsV[((st_t*3+1)*4 + k8)*128 + st_row] = make_int4(d1[0], d1[1], d1[2], d1[3]);
            AsV[((st_t*3+2)*4 + k8)*128 + st_row] = make_int4(d2[0], d2[1], d2[2], d2[3]);
        }
        if (kc < 7) {
            const float* Agn = Ag + (kc + 1) * 32;
            #pragma unroll
            for (int q = 0; q < 4; ++q)
                *(float4*)&va[q*4] = *(const float4*)(Agn + q*4);
        }
        __syncthreads();   // LDS tile ready

        #pragma unroll
        for (int t = 0; t < 2; ++t) {
            bf16x8 af[3][4];
            #pragma unroll
            for (int p = 0; p < 3; ++p)
                #pragma unroll
                for (int rf = 0; rf < 4; ++rf)
                    af[p][rf] = *(const bf16x8*)&AsV[((t*3+p)*4 + (l>>4))*128 + rw + rf*16 + (l & 15)];
            #pragma unroll
            for (int j = 0; j < 3; ++j) {
                bf16x8 bfr[4];
                #pragma unroll
                for (int cf = 0; cf < 4; ++cf)
                    bfr[cf] = *(const bf16x8*)&wsplit[(((t*3 + j)*16 + (nw>>4) + cf)*8 + kc)*64 + l];
                #pragma unroll
                for (int i = 0; i + j < 3; ++i)
                    #pragma unroll
                    for (int rf = 0; rf < 4; ++rf)
                        #pragma unroll
                        for (int cf = 0; cf < 4; ++cf)
                            acc[t][rf][cf] = __builtin_amdgcn_mfma_f32_16x16x32_bf16(
                                af[i][rf], bfr[cf], acc[t][rf][cf], 0, 0, 0);
            }
        }
    }

    // epilogue: gates + cross fuse. C/D layout: col = lane&15, row = (lane>>4)*4 + reg.
    float ba4[4], bl4[4];
    #pragma unroll
    for (int cf = 0; cf < 4; ++cf) {
        const int n = nw + cf*16 + (l & 15);
        ba4[cf] = ba[n];
        bl4[cf] = bl[n];
    }
    #pragma unroll
    for (int rf = 0; rf < 4; ++rf)
        #pragma unroll
        for (int r = 0; r < 4; ++r) {
            const size_t rowb = (size_t)(m0 + rw + rf*16 + (l >> 4)*4 + r) * 256;
            #pragma unroll
            for (int cf = 0; cf < 4; ++cf) {
                const int n = nw + cf*16 + (l & 15);
                const float g_lsm  = sigmoidf_(acc[0][rf][cf][r] + ba4[cf]); // sigmoid(a.W_att + b_att)
                const float g_attn = sigmoidf_(acc[1][rf][cf][r] + bl4[cf]); // sigmoid(l.W_lsm + b_lsm)
                const float av = A1[rowb + n], lv = A2[rowb + n];
                fused[rowb + n] = av * g_attn + lv * g_lsm;
            }
        }
}

// ---------------------------------------------------------------------------
// K2: out = fused . W_proj^T + b_proj (fp32 VALU — R2/R13 champion, verbatim),
//     plus per-block per-channel partial sum / sumsq for BatchNorm.
// ---------------------------------------------------------------------------
__global__ __launch_bounds__(256) void k2_proj(
    const float* __restrict__ F,    // fused (M, C)
    const float* __restrict__ Wp,   // W_proj (d, c)
    const float* __restrict__ bp,
    float* __restrict__ out,        // (M, C) pre-BN
    float* __restrict__ psum,       // [C][MTILES]
    float* __restrict__ psumsq)     // [C][MTILES]
{
    __shared__ float As[BK][LDP];
    __shared__ float Ws[BK][LDP];
    __shared__ float redS[BN][17];
    __shared__ float redQ[BN][17];

    const int tid  = threadIdx.x;
    const int tx   = tid & 15;
    const int ty   = tid >> 4;
    const int row0 = blockIdx.x * BM;
    const int col0 = blockIdx.y * BN;
    const int lr   = tid >> 2;
    const int lk   = (tid & 3) << 2;

    float acc[4][4] = {};

    const float* pF = F  + (size_t)(row0 + lr) * CCH + lk;
    const float* pW = Wp + (size_t)(col0 + lr) * CCH + lk;

    for (int k0 = 0; k0 < CCH; k0 += BK) {
        float4 f4 = *(const float4*)(pF + k0);
        float4 w4 = *(const float4*)(pW + k0);
        As[lk+0][lr] = f4.x; As[lk+1][lr] = f4.y; As[lk+2][lr] = f4.z; As[lk+3][lr] = f4.w;
        Ws[lk+0][lr] = w4.x; Ws[lk+1][lr] = w4.y; Ws[lk+2][lr] = w4.z; Ws[lk+3][lr] = w4.w;
        __syncthreads();
        #pragma unroll
        for (int kk = 0; kk < BK; ++kk) {
            float ar[4], wr[4];
            *(float4*)ar = *(const float4*)&As[kk][ty << 2];
            *(float4*)wr = *(const float4*)&Ws[kk][tx << 2];
            #pragma unroll
            for (int i = 0; i < 4; ++i)
                #pragma unroll
                for (int j = 0; j < 4; ++j)
                    acc[i][j] = fmaf(ar[i], wr[j], acc[i][j]);
        }
        __syncthreads();
    }

    float bp_[4];
    *(float4*)bp_ = *(const float4*)(bp + col0 + (tx << 2));
    float sj[4] = {}, qj[4] = {};
    #pragma unroll
    for (int i = 0; i < 4; ++i) {
        const int m = row0 + (ty << 2) + i;
        float o_[4];
        #pragma unroll
        for (int j = 0; j < 4; ++j) {
            o_[j] = acc[i][j] + bp_[j];
            sj[j] += o_[j];
            qj[j] += o_[j] * o_[j];
        }
        *(float4*)(out + (size_t)m * CCH + col0 + (tx << 2)) = *(float4*)o_;
    }
    #pragma unroll
    for (int j = 0; j < 4; ++j) {
        redS[(tx << 2) + j][ty] = sj[j];
        redQ[(tx << 2) + j][ty] = qj[j];
    }
    __syncthreads();
    if (tid < BN) {
        float s = 0.f, q = 0.f;
        #pragma unroll
        for (int u = 0; u < 16; ++u) { s += redS[tid][u]; q += redQ[tid][u]; }
        psum  [(size_t)(col0 + tid) * MTILES + blockIdx.x] = s;
        psumsq[(size_t)(col0 + tid) * MTILES + blockIdx.x] = q;
    }
}

// ---------------------------------------------------------------------------
// K3: per-channel fp64 reduction of partials -> mean, inv_std
// ---------------------------------------------------------------------------
__global__ __launch_bounds__(256) void k3_stats(
    const float* __restrict__ psum,
    const float* __restrict__ psumsq,
    float* __restrict__ stats)   // [0..255]=mean, [256..511]=inv_std
{
    const int c = blockIdx.x;
    const int tid = threadIdx.x;
    double s = 0.0, q = 0.0;
    for (int i = tid; i < MTILES; i += 256) {
        s += (double)psum  [(size_t)c * MTILES + i];
        q += (double)psumsq[(size_t)c * MTILES + i];
    }
    __shared__ double sd[256];
    __shared__ double qd[256];
    sd[tid] = s; qd[tid] = q;
    __syncthreads();
    for (int off = 128; off > 0; off >>= 1) {
        if (tid < off) { sd[tid] += sd[tid + off]; qd[tid] += qd[tid + off]; }
        __syncthreads();
    }
    if (tid == 0) {
        const double inv_m = 1.0 / (double)MROWS;
        const double mean = sd[0] * inv_m;
        const double var  = qd[0] * inv_m - mean * mean;
        stats[c]        = (float)mean;
        stats[256 + c]  = (float)(1.0 / sqrt(var + 1e-5));
    }
}

// ---------------------------------------------------------------------------
// K4 v2: BN-normalize + 4-step parametric LIF, in place on d_out.
// 2 sites (8 channels) per thread; both loads issued before compute (2x VMEM
// in flight); non-temporal stores via clang ext_vector f32x4 (spikes are
// never re-read on device). Per-element math IDENTICAL to R13's k4.
// ---------------------------------------------------------------------------
__global__ __launch_bounds__(256) void k4_lif(
    float* __restrict__ out,          // in: pre-BN out; out: spikes
    const float* __restrict__ stats,
    const float* __restrict__ gamma,
    const float* __restrict__ beta,
    const float* __restrict__ lifw)
{
    const size_t gid  = (size_t)blockIdx.x * 256 + threadIdx.x;
    const size_t base = gid * 8;                 // element index within a T-slice
    const int c0 = (int)(base & (CCH - 1));      // multiple of 8

    const float tau = 1.0f / (1.0f + expf(-lifw[0]));

    float mean_[8], istd_[8], g_[8], b_[8];
    *(float4*)&mean_[0] = *(const float4*)(stats + c0);
    *(float4*)&mean_[4] = *(const float4*)(stats + c0 + 4);
    *(float4*)&istd_[0] = *(const float4*)(stats + 256 + c0);
    *(float4*)&istd_[4] = *(const float4*)(stats + 256 + c0 + 4);
    *(float4*)&g_[0]    = *(const float4*)(gamma + c0);
    *(float4*)&g_[4]    = *(const float4*)(gamma + c0 + 4);
    *(float4*)&b_[0]    = *(const float4*)(beta + c0);
    *(float4*)&b_[4]    = *(const float4*)(beta + c0 + 4);

    float v[8] = {0.f, 0.f, 0.f, 0.f, 0.f, 0.f, 0.f, 0.f};
    #pragma unroll
    for (int t = 0; t < TSTEPS; ++t) {
        float x_[8], s_[8];
        // issue both loads before any compute (2 VMEM in flight)
        float4 xa = *(const float4*)(out + (size_t)t * SSLICE + base);
        float4 xb = *(const float4*)(out + (size_t)t * SSLICE + base + 4);
        *(float4*)&x_[0] = xa;
        *(float4*)&x_[4] = xb;
        #pragma unroll
        for (int j = 0; j < 8; ++j) {
            const float y = g_[j] * (x_[j] - mean_[j]) * istd_[j] + b_[j];
            v[j] = v[j] + (y - v[j]) * tau;
            s_[j] = (v[j] >= 1.0f) ? 1.0f : 0.0f;
            v[j] *= (1.0f - s_[j]);
        }
        __builtin_nontemporal_store(*(f32x4*)&s_[0], (f32x4*)(out + (size_t)t * SSLICE + base));
        __builtin_nontemporal_store(*(f32x4*)&s_[4], (f32x4*)(out + (size_t)t * SSLICE + base + 4));
    }
}

// ---------------------------------------------------------------------------
extern "C" void kernel_launch(void* const* d_in, const int* in_sizes, int n_in,
                              void* d_out, int out_size, void* d_ws, size_t ws_size,
                              hipStream_t stream) {
    const float* x_attn = (const float*)d_in[0];
    const float* x_lsm  = (const float*)d_in[1];
    const float* W_att  = (const float*)d_in[2];
    const float* b_att  = (const float*)d_in[3];
    const float* W_lsm  = (const float*)d_in[4];
    const float* b_lsm  = (const float*)d_in[5];
    const float* W_proj = (const float*)d_in[6];
    const float* b_proj = (const float*)d_in[7];
    const float* gamma  = (const float*)d_in[8];
    const float* beta   = (const float*)d_in[9];
    const float* lif_w  = (const float*)d_in[10];

    float* out = (float*)d_out;

    // ws carve — EXACT R2/R13-proven layout (138,414,080 B):
    char* w = (char*)d_ws;
    float* fused  = (float*)w;                                   // 134,217,728 B
    float* psum   = (float*)(w + 134217728ull);                  // 2,097,152 B
    float* psumsq = (float*)(w + 134217728ull + 2097152ull);     // 2,097,152 B
    float* stats  = (float*)(w + 134217728ull + 4194304ull);     // 2,048 B
    // wsplit (786 KB) OVERLAYS psum: consumed by k0/k1 strictly before k2 writes psum.
    int4*  wsplit = (int4*)(w + 134217728ull);

    dim3 blk(256);
    dim3 g2(MROWS / BM, CCH / BN);   // (2048, 4) for k2

    k0_splitw<<<dim3(64),   blk, 0, stream>>>(W_att, W_lsm, wsplit);
    k1_mfma  <<<dim3(1024), dim3(512), 0, stream>>>(x_attn, x_lsm, wsplit, b_att, b_lsm, fused);
    k2_proj  <<<g2, blk, 0, stream>>>(fused, W_proj, b_proj, out, psum, psumsq);
    k3_stats <<<dim3(CCH), blk, 0, stream>>>(psum, psumsq, stats);
    k4_lif   <<<dim3((SSLICE / 8) / 256), blk, 0, stream>>>(out, stats, gamma, beta, lif_w);
}

// Round 16
// 530.381 us; speedup vs baseline: 1.0300x; 1.0300x over previous
//
#include <hip/hip_runtime.h>
#include <math.h>

// Problem geometry (fixed by reference): T=4, B=32, N=1024, C=256
#define MROWS   131072      // T*B*N rows, C contiguous
#define CCH     256
#define TSTEPS  4
#define SSLICE  8388608     // B*N*C (one timestep slice)
#define BM      64
#define BN      64
#define BK      16
#define LDP     68
#define MTILES  2048        // MROWS/BM (for k2 partials)

typedef float  f32x4  __attribute__((ext_vector_type(4)));
typedef short  bf16x8 __attribute__((ext_vector_type(8)));

__device__ __forceinline__ float sigmoidf_(float x) {
    return 1.0f / (1.0f + __expf(-x));
}

// Exact 3-way bf16 split of a pair of fp32 values, packed k-pairwise into dwords.
// d0 = (bf16hi(y0)<<16)|bf16hi(x0) etc. Pack order identical for A and B paths,
// so any pack-order convention cancels inside MFMA.
__device__ __forceinline__ void split_pair(float x, float y, unsigned& d0, unsigned& d1, unsigned& d2) {
    unsigned ux = __float_as_uint(x), uy = __float_as_uint(y);
    unsigned ux0 = ux & 0xffff0000u, uy0 = uy & 0xffff0000u;
    float rx = x - __uint_as_float(ux0), ry = y - __uint_as_float(uy0);
    unsigned ux1 = __float_as_uint(rx) & 0xffff0000u, uy1 = __float_as_uint(ry) & 0xffff0000u;
    float r2x = rx - __uint_as_float(ux1), r2y = ry - __uint_as_float(uy1);
    d0 = __builtin_amdgcn_perm(uy0, ux0, 0x07060302u);
    d1 = __builtin_amdgcn_perm(uy1, ux1, 0x07060302u);
    unsigned pk;
    asm("v_cvt_pk_bf16_f32 %0, %1, %2" : "=v"(pk) : "v"(r2x), "v"(r2y));
    d2 = pk;
}

// ---------------------------------------------------------------------------
// K0: pre-split W_att, W_lsm into bf16x3 planes, frag-ordered:
// wsplit[(((t*3+p)*16 + ncf)*8 + kc)*64 + l] = 16B chunk for lane l:
//   n = ncf*16 + (l&15), k = kc*32 + (l>>4)*8 + e
// ---------------------------------------------------------------------------
__global__ __launch_bounds__(256) void k0_splitw(
    const float* __restrict__ Wa, const float* __restrict__ Wl,
    int4* __restrict__ wsplit)
{
    const int gid = blockIdx.x * 256 + threadIdx.x;  // 0..16383
    const int t   = gid >> 13;
    const int rem = gid & 8191;
    const int ncf = rem >> 9;         // 0..15
    const int kc  = (rem >> 6) & 7;   // 0..7
    const int l   = rem & 63;
    const int n   = ncf * 16 + (l & 15);
    const int k0  = kc * 32 + (l >> 4) * 8;
    const float* W = t ? Wl : Wa;

    float v[8];
    *(float4*)&v[0] = *(const float4*)(W + n * 256 + k0);
    *(float4*)&v[4] = *(const float4*)(W + n * 256 + k0 + 4);

    unsigned d0[4], d1[4], d2[4];
    #pragma unroll
    for (int j = 0; j < 4; ++j)
        split_pair(v[2*j], v[2*j+1], d0[j], d1[j], d2[j]);

    wsplit[(((t*3+0)*16 + ncf)*8 + kc)*64 + l] = make_int4(d0[0], d0[1], d0[2], d0[3]);
    wsplit[(((t*3+1)*16 + ncf)*8 + kc)*64 + l] = make_int4(d1[0], d1[1], d1[2], d1[3]);
    wsplit[(((t*3+2)*16 + ncf)*8 + kc)*64 + l] = make_int4(d2[0], d2[1], d2[2], d2[3]);
}

// ---------------------------------------------------------------------------
// K1: dual GEMM via bf16x3-split MFMA emulation + sigmoid gates + cross fuse.
// BM=128, BN=256 (full N), 512 threads = 8 waves (2M x 4N), wave tile 64x64.
// A (x_attn, x_lsm) split in-kernel into LDS; B from pre-split planes (L2-hot).
// EXACT R2/R13 champion: single-buffered LDS, 2 barriers/kc, NO setprio.
// ---------------------------------------------------------------------------
__global__ __launch_bounds__(512, 2) void k1_mfma(
    const float* __restrict__ A1, const float* __restrict__ A2,
    const int4* __restrict__ wsplit,
    const float* __restrict__ ba, const float* __restrict__ bl,
    float* __restrict__ fused)
{
    __shared__ int4 AsV[2*3*4*128];   // [t][p][k8][row] 16B chunks = 48 KB

    const int tid = threadIdx.x;
    const int l   = tid & 63;
    const int w   = tid >> 6;
    const int rw  = (w >> 2) * 64;    // wave M offset
    const int nw  = (w & 3) * 64;     // wave N offset
    const int m0  = blockIdx.x * 128;

    // staging assignment: 512 threads cover 2 tensors x 128 rows x 2 k-halves
    const int st_t   = tid >> 8;
    const int st_row = (tid & 255) >> 1;
    const int st_kh  = tid & 1;
    const float* Ag  = (st_t ? A2 : A1) + (size_t)(m0 + st_row) * 256 + st_kh * 16;

    f32x4 acc[2][4][4] = {};

    float va[16];
    #pragma unroll
    for (int q = 0; q < 4; ++q)
        *(float4*)&va[q*4] = *(const float4*)(Ag + q*4);

    for (int kc = 0; kc < 8; ++kc) {
        __syncthreads();   // previous compute done reading LDS
        #pragma unroll
        for (int g = 0; g < 2; ++g) {
            unsigned d0[4], d1[4], d2[4];
            #pragma unroll
            for (int j = 0; j < 4; ++j)
                split_pair(va[g*8 + 2*j], va[g*8 + 2*j + 1], d0[j], d1[j], d2[j]);
            const int k8 = st_kh * 2 + g;
            AsV[((st_t*3+0)*4 + k8)*128 + st_row] = make_int4(d0[0], d0[1], d0[2], d0[3]);
            AsV[((st_t*3+1)*4 + k8)*128 + st_row] = make_int4(d1[0], d1[1], d1[2], d1[3]);
            AsV[((st_t*3+2)*4 + k8)*128 + st_row] = make_int4(d2[0], d2[1], d2[2], d2[3]);
        }
        if (kc < 7) {
            const float* Agn = Ag + (kc + 1) * 32;
            #pragma unroll
            for (int q = 0; q < 4; ++q)
                *(float4*)&va[q*4] = *(const float4*)(Agn + q*4);
        }
        __syncthreads();   // LDS tile ready

        #pragma unroll
        for (int t = 0; t < 2; ++t) {
            bf16x8 af[3][4];
            #pragma unroll
            for (int p = 0; p < 3; ++p)
                #pragma unroll
                for (int rf = 0; rf < 4; ++rf)
                    af[p][rf] = *(const bf16x8*)&AsV[((t*3+p)*4 + (l>>4))*128 + rw + rf*16 + (l & 15)];
            #pragma unroll
            for (int j = 0; j < 3; ++j) {
                bf16x8 bfr[4];
                #pragma unroll
                for (int cf = 0; cf < 4; ++cf)
                    bfr[cf] = *(const bf16x8*)&wsplit[(((t*3 + j)*16 + (nw>>4) + cf)*8 + kc)*64 + l];
                #pragma unroll
                for (int i = 0; i + j < 3; ++i)
                    #pragma unroll
                    for (int rf = 0; rf < 4; ++rf)
                        #pragma unroll
                        for (int cf = 0; cf < 4; ++cf)
                            acc[t][rf][cf] = __builtin_amdgcn_mfma_f32_16x16x32_bf16(
                                af[i][rf], bfr[cf], acc[t][rf][cf], 0, 0, 0);
            }
        }
    }

    // epilogue: gates + cross fuse. C/D layout: col = lane&15, row = (lane>>4)*4 + reg.
    float ba4[4], bl4[4];
    #pragma unroll
    for (int cf = 0; cf < 4; ++cf) {
        const int n = nw + cf*16 + (l & 15);
        ba4[cf] = ba[n];
        bl4[cf] = bl[n];
    }
    #pragma unroll
    for (int rf = 0; rf < 4; ++rf)
        #pragma unroll
        for (int r = 0; r < 4; ++r) {
            const size_t rowb = (size_t)(m0 + rw + rf*16 + (l >> 4)*4 + r) * 256;
            #pragma unroll
            for (int cf = 0; cf < 4; ++cf) {
                const int n = nw + cf*16 + (l & 15);
                const float g_lsm  = sigmoidf_(acc[0][rf][cf][r] + ba4[cf]); // sigmoid(a.W_att + b_att)
                const float g_attn = sigmoidf_(acc[1][rf][cf][r] + bl4[cf]); // sigmoid(l.W_lsm + b_lsm)
                const float av = A1[rowb + n], lv = A2[rowb + n];
                fused[rowb + n] = av * g_attn + lv * g_lsm;
            }
        }
}

// ---------------------------------------------------------------------------
// K2: out = fused . W_proj^T + b_proj (fp32 VALU — R2/R13 champion, verbatim),
//     plus per-block per-channel partial sum / sumsq for BatchNorm.
// ---------------------------------------------------------------------------
__global__ __launch_bounds__(256) void k2_proj(
    const float* __restrict__ F,    // fused (M, C)
    const float* __restrict__ Wp,   // W_proj (d, c)
    const float* __restrict__ bp,
    float* __restrict__ out,        // (M, C) pre-BN
    float* __restrict__ psum,       // [C][MTILES]
    float* __restrict__ psumsq)     // [C][MTILES]
{
    __shared__ float As[BK][LDP];
    __shared__ float Ws[BK][LDP];
    __shared__ float redS[BN][17];
    __shared__ float redQ[BN][17];

    const int tid  = threadIdx.x;
    const int tx   = tid & 15;
    const int ty   = tid >> 4;
    const int row0 = blockIdx.x * BM;
    const int col0 = blockIdx.y * BN;
    const int lr   = tid >> 2;
    const int lk   = (tid & 3) << 2;

    float acc[4][4] = {};

    const float* pF = F  + (size_t)(row0 + lr) * CCH + lk;
    const float* pW = Wp + (size_t)(col0 + lr) * CCH + lk;

    for (int k0 = 0; k0 < CCH; k0 += BK) {
        float4 f4 = *(const float4*)(pF + k0);
        float4 w4 = *(const float4*)(pW + k0);
        As[lk+0][lr] = f4.x; As[lk+1][lr] = f4.y; As[lk+2][lr] = f4.z; As[lk+3][lr] = f4.w;
        Ws[lk+0][lr] = w4.x; Ws[lk+1][lr] = w4.y; Ws[lk+2][lr] = w4.z; Ws[lk+3][lr] = w4.w;
        __syncthreads();
        #pragma unroll
        for (int kk = 0; kk < BK; ++kk) {
            float ar[4], wr[4];
            *(float4*)ar = *(const float4*)&As[kk][ty << 2];
            *(float4*)wr = *(const float4*)&Ws[kk][tx << 2];
            #pragma unroll
            for (int i = 0; i < 4; ++i)
                #pragma unroll
                for (int j = 0; j < 4; ++j)
                    acc[i][j] = fmaf(ar[i], wr[j], acc[i][j]);
        }
        __syncthreads();
    }

    float bp_[4];
    *(float4*)bp_ = *(const float4*)(bp + col0 + (tx << 2));
    float sj[4] = {}, qj[4] = {};
    #pragma unroll
    for (int i = 0; i < 4; ++i) {
        const int m = row0 + (ty << 2) + i;
        float o_[4];
        #pragma unroll
        for (int j = 0; j < 4; ++j) {
            o_[j] = acc[i][j] + bp_[j];
            sj[j] += o_[j];
            qj[j] += o_[j] * o_[j];
        }
        *(float4*)(out + (size_t)m * CCH + col0 + (tx << 2)) = *(float4*)o_;
    }
    #pragma unroll
    for (int j = 0; j < 4; ++j) {
        redS[(tx << 2) + j][ty] = sj[j];
        redQ[(tx << 2) + j][ty] = qj[j];
    }
    __syncthreads();
    if (tid < BN) {
        float s = 0.f, q = 0.f;
        #pragma unroll
        for (int u = 0; u < 16; ++u) { s += redS[tid][u]; q += redQ[tid][u]; }
        psum  [(size_t)(col0 + tid) * MTILES + blockIdx.x] = s;
        psumsq[(size_t)(col0 + tid) * MTILES + blockIdx.x] = q;
    }
}

// ---------------------------------------------------------------------------
// K3: per-channel fp64 reduction of partials -> mean, inv_std
// ---------------------------------------------------------------------------
__global__ __launch_bounds__(256) void k3_stats(
    const float* __restrict__ psum,
    const float* __restrict__ psumsq,
    float* __restrict__ stats)   // [0..255]=mean, [256..511]=inv_std
{
    const int c = blockIdx.x;
    const int tid = threadIdx.x;
    double s = 0.0, q = 0.0;
    for (int i = tid; i < MTILES; i += 256) {
        s += (double)psum  [(size_t)c * MTILES + i];
        q += (double)psumsq[(size_t)c * MTILES + i];
    }
    __shared__ double sd[256];
    __shared__ double qd[256];
    sd[tid] = s; qd[tid] = q;
    __syncthreads();
    for (int off = 128; off > 0; off >>= 1) {
        if (tid < off) { sd[tid] += sd[tid + off]; qd[tid] += qd[tid + off]; }
        __syncthreads();
    }
    if (tid == 0) {
        const double inv_m = 1.0 / (double)MROWS;
        const double mean = sd[0] * inv_m;
        const double var  = qd[0] * inv_m - mean * mean;
        stats[c]        = (float)mean;
        stats[256 + c]  = (float)(1.0 / sqrt(var + 1e-5));
    }
}

// ---------------------------------------------------------------------------
// K4: BN-normalize + 4-step parametric LIF, in place on d_out.
// R13 champion version: 1 site (4 channels) per thread — measured optimal
// (R15's 2-site + nontemporal variant regressed ~11 us).
// ---------------------------------------------------------------------------
__global__ __launch_bounds__(256) void k4_lif(
    float* __restrict__ out,          // in: pre-BN out; out: spikes
    const float* __restrict__ stats,
    const float* __restrict__ gamma,
    const float* __restrict__ beta,
    const float* __restrict__ lifw)
{
    const size_t gid  = (size_t)blockIdx.x * 256 + threadIdx.x;
    const size_t base = gid * 4;                 // element index within a T-slice
    const int c0 = (int)(base & (CCH - 1));

    const float tau = 1.0f / (1.0f + expf(-lifw[0]));

    float mean_[4], istd_[4], g_[4], b_[4];
    *(float4*)mean_ = *(const float4*)(stats + c0);
    *(float4*)istd_ = *(const float4*)(stats + 256 + c0);
    *(float4*)g_    = *(const float4*)(gamma + c0);
    *(float4*)b_    = *(const float4*)(beta + c0);

    float v[4] = {0.f, 0.f, 0.f, 0.f};
    #pragma unroll
    for (int t = 0; t < TSTEPS; ++t) {
        float x_[4], s_[4];
        *(float4*)x_ = *(const float4*)(out + (size_t)t * SSLICE + base);
        #pragma unroll
        for (int j = 0; j < 4; ++j) {
            const float y = g_[j] * (x_[j] - mean_[j]) * istd_[j] + b_[j];
            v[j] = v[j] + (y - v[j]) * tau;
            s_[j] = (v[j] >= 1.0f) ? 1.0f : 0.0f;
            v[j] *= (1.0f - s_[j]);
        }
        *(float4*)(out + (size_t)t * SSLICE + base) = *(float4*)s_;
    }
}

// ---------------------------------------------------------------------------
extern "C" void kernel_launch(void* const* d_in, const int* in_sizes, int n_in,
                              void* d_out, int out_size, void* d_ws, size_t ws_size,
                              hipStream_t stream) {
    const float* x_attn = (const float*)d_in[0];
    const float* x_lsm  = (const float*)d_in[1];
    const float* W_att  = (const float*)d_in[2];
    const float* b_att  = (const float*)d_in[3];
    const float* W_lsm  = (const float*)d_in[4];
    const float* b_lsm  = (const float*)d_in[5];
    const float* W_proj = (const float*)d_in[6];
    const float* b_proj = (const float*)d_in[7];
    const float* gamma  = (const float*)d_in[8];
    const float* beta   = (const float*)d_in[9];
    const float* lif_w  = (const float*)d_in[10];

    float* out = (float*)d_out;

    // ws carve — EXACT R2/R13-proven layout (138,414,080 B):
    char* w = (char*)d_ws;
    float* fused  = (float*)w;                                   // 134,217,728 B
    float* psum   = (float*)(w + 134217728ull);                  // 2,097,152 B
    float* psumsq = (float*)(w + 134217728ull + 2097152ull);     // 2,097,152 B
    float* stats  = (float*)(w + 134217728ull + 4194304ull);     // 2,048 B
    // wsplit (786 KB) OVERLAYS psum: consumed by k0/k1 strictly before k2 writes psum.
    int4*  wsplit = (int4*)(w + 134217728ull);

    dim3 blk(256);
    dim3 g2(MROWS / BM, CCH / BN);   // (2048, 4) for k2

    k0_splitw<<<dim3(64),   blk, 0, stream>>>(W_att, W_lsm, wsplit);
    k1_mfma  <<<dim3(1024), dim3(512), 0, stream>>>(x_attn, x_lsm, wsplit, b_att, b_lsm, fused);
    k2_proj  <<<g2, blk, 0, stream>>>(fused, W_proj, b_proj, out, psum, psumsq);
    k3_stats <<<dim3(CCH), blk, 0, stream>>>(psum, psumsq, stats);
    k4_lif   <<<dim3((SSLICE / 4) / 256), blk, 0, stream>>>(out, stats, gamma, beta, lif_w);
}